// Round 1
// baseline (658.800 us; speedup 1.0000x reference)
//
#include <hip/hip_runtime.h>

typedef unsigned short u16;
typedef unsigned int   u32;
typedef float  f32x4  __attribute__((ext_vector_type(4)));
typedef __bf16 bf16x8 __attribute__((ext_vector_type(8)));

#define B_N   8
#define T_N   1500
#define D_N   512
#define K_N   4096
#define NTOK  12000
#define STRD  320

// ---- workspace byte offsets (total ~28.9 MB) ----
#define X2S_OFF    0u                       // 12000 floats
#define C2_OFF     49152u                   // 4096 floats
#define FEATP_OFF  65536u                   // 3000 floats
#define TRIPP_OFF  81920u                   // 3000 floats
#define SOFTP_OFF  98304u                   // 750 floats
#define COMMP_OFF  106496u                  // 750 floats
#define SBF_OFF    131072u                  // 12000*512 u16 (bf16 student)
#define TBF_OFF    (131072u + 12288000u)    // 12000*512 u16 (bf16 teacher)
#define CBBF_OFF   (131072u + 24576000u)    // 4096*512 u16 (bf16 codebook)

__device__ __forceinline__ u16 f2bf(float x){
  u32 u = __float_as_uint(x);
  u32 r = (u + 0x7fffu + ((u >> 16) & 1u)) >> 16;   // round-nearest-even
  return (u16)r;
}

__device__ __forceinline__ void gl_lds16(const void* g, void* l){
  // async global->LDS, 16B/lane; LDS dest = wave-uniform base + lane*16
  __builtin_amdgcn_global_load_lds(
      (__attribute__((address_space(1))) void*)(g),
      (__attribute__((address_space(3))) void*)(l),
      16, 0, 0);
}

// ============ prep 1: per-token stats, bf16 casts, feature+triplet ============
__global__ __launch_bounds__(256) void prep_feat_kernel(
    const float* __restrict__ s, const float* __restrict__ t,
    const int* __restrict__ lengths,
    u16* __restrict__ sbf, u16* __restrict__ tbf,
    float* __restrict__ x2s,
    float* __restrict__ featP, float* __restrict__ tripP)
{
  const int tid = threadIdx.x;
  const int w = tid >> 6, lane = tid & 63;
  const int n = blockIdx.x * 4 + w;                 // one wave per token
  const int b = n / T_N, tt = n - b * T_N;
  const int nr = ((b + 7) & 7) * T_N + tt;          // roll(teacher, +1, axis=0)

  const float4* sp = (const float4*)(s + (size_t)n  * D_N);
  const float4* tp = (const float4*)(t + (size_t)n  * D_N);
  const float4* rp = (const float4*)(t + (size_t)nr * D_N);
  float4 s0 = sp[lane*2], s1 = sp[lane*2+1];
  float4 t0 = tp[lane*2], t1 = tp[lane*2+1];
  float4 r0 = rp[lane*2], r1 = rp[lane*2+1];

  float sv[8] = {s0.x,s0.y,s0.z,s0.w,s1.x,s1.y,s1.z,s1.w};
  float tv[8] = {t0.x,t0.y,t0.z,t0.w,t1.x,t1.y,t1.z,t1.w};
  float rv[8] = {r0.x,r0.y,r0.z,r0.w,r1.x,r1.y,r1.z,r1.w};

  float sd2 = 0.f, x2 = 0.f, nd2 = 0.f;
  u16 sb[8], tb[8];
#pragma unroll
  for (int i = 0; i < 8; ++i){
    float d = sv[i] - tv[i]; sd2 += d*d;
    x2 += sv[i]*sv[i];
    float e = sv[i] - rv[i]; nd2 += e*e;
    sb[i] = f2bf(sv[i]); tb[i] = f2bf(tv[i]);
  }
  uint4 spk, tpk;
  spk.x = (u32)sb[0] | ((u32)sb[1] << 16);
  spk.y = (u32)sb[2] | ((u32)sb[3] << 16);
  spk.z = (u32)sb[4] | ((u32)sb[5] << 16);
  spk.w = (u32)sb[6] | ((u32)sb[7] << 16);
  tpk.x = (u32)tb[0] | ((u32)tb[1] << 16);
  tpk.y = (u32)tb[2] | ((u32)tb[3] << 16);
  tpk.z = (u32)tb[4] | ((u32)tb[5] << 16);
  tpk.w = (u32)tb[6] | ((u32)tb[7] << 16);
  ((uint4*)(sbf + (size_t)n * D_N))[lane] = spk;
  ((uint4*)(tbf + (size_t)n * D_N))[lane] = tpk;

#pragma unroll
  for (int mm = 1; mm < 64; mm <<= 1){
    sd2 += __shfl_xor(sd2, mm);
    x2  += __shfl_xor(x2,  mm);
    nd2 += __shfl_xor(nd2, mm);
  }

  __shared__ float af[4], atr[4];
  if (lane == 0){
    x2s[n] = x2;
    int valid = lengths[b] / STRD; if (valid > T_N) valid = T_N;
    float mf = (tt < valid) ? 1.f : 0.f;
    af[w]  = mf * sd2 * (1.f/512.f);
    atr[w] = mf * fmaxf(sqrtf(sd2) - sqrtf(nd2) + 0.2f, 0.f);
  }
  __syncthreads();
  if (tid == 0){
    featP[blockIdx.x] = af[0]+af[1]+af[2]+af[3];
    tripP[blockIdx.x] = atr[0]+atr[1]+atr[2]+atr[3];
  }
}

// ============ prep 2: codebook norms + bf16 cast ============
__global__ __launch_bounds__(256) void prep_cb_kernel(
    const float* __restrict__ cb, u16* __restrict__ cbbf, float* __restrict__ c2)
{
  const int tid = threadIdx.x;
  const int w = tid >> 6, lane = tid & 63;
  const int k = blockIdx.x * 4 + w;

  const float4* cp = (const float4*)(cb + (size_t)k * D_N);
  float4 c0 = cp[lane*2], c1 = cp[lane*2+1];
  float cv[8] = {c0.x,c0.y,c0.z,c0.w,c1.x,c1.y,c1.z,c1.w};

  float s2 = 0.f;
  u16 cbv[8];
#pragma unroll
  for (int i = 0; i < 8; ++i){ s2 += cv[i]*cv[i]; cbv[i] = f2bf(cv[i]); }
  uint4 pk;
  pk.x = (u32)cbv[0] | ((u32)cbv[1] << 16);
  pk.y = (u32)cbv[2] | ((u32)cbv[3] << 16);
  pk.z = (u32)cbv[4] | ((u32)cbv[5] << 16);
  pk.w = (u32)cbv[6] | ((u32)cbv[7] << 16);
  ((uint4*)(cbbf + (size_t)k * D_N))[lane] = pk;

#pragma unroll
  for (int mm = 1; mm < 64; mm <<= 1) s2 += __shfl_xor(s2, mm);
  if (lane == 0) c2[k] = s2;
}

// ============ main: fused dual-GEMM + online-softmax KL + min-dist ============
// block: 256 thr (4 waves), M=16 tokens, code tiles of 64 (wave w -> 16 codes),
// D chunks of 128 staged via global_load_lds. 750 blocks.
__global__ __launch_bounds__(256, 3) void main_kl_kernel(
    const u16* __restrict__ sbf, const u16* __restrict__ tbf,
    const u16* __restrict__ cbbf, const float* __restrict__ c2,
    const float* __restrict__ x2s, const int* __restrict__ lengths,
    float* __restrict__ softP, float* __restrict__ commP)
{
  __shared__ u16 As[16*512];      // 16 KB
  __shared__ u16 At[16*512];      // 16 KB
  __shared__ u16 Bc[64*128];      // 16 KB
  __shared__ float wst[4][16][5]; // cross-wave merge buffer

  const int tid  = threadIdx.x;
  const int w    = tid >> 6, lane = tid & 63;
  const int quad = lane >> 4, lc = lane & 15;
  const int blk  = blockIdx.x;

  // ---- stage A (once): 16 tokens x 512 d, s and t ----
  {
    const u16* sg = sbf + (size_t)blk * 16 * 512;
    const u16* tg = tbf + (size_t)blk * 16 * 512;
#pragma unroll
    for (int j = 0; j < 4; ++j){
      int off = (w*4 + j)*512 + lane*8;   // 1KB chunks, lane*16B inside
      gl_lds16(sg + off, &As[off]);
      gl_lds16(tg + off, &At[off]);
    }
  }

  // per-lane online-softmax partial state for tokens quad*4+i,
  // codes == class (w, lc) mod 64
  float mS[4], ZS[4], mT[4], ZT[4], AA[4];
#pragma unroll
  for (int i = 0; i < 4; ++i){ mS[i] = -1e30f; mT[i] = -1e30f; ZS[i]=0.f; ZT[i]=0.f; AA[i]=0.f; }

  f32x4 accS = {0.f,0.f,0.f,0.f}, accT = {0.f,0.f,0.f,0.f};

  for (int kt = 0; kt < 64; ++kt){
    for (int cc = 0; cc < 4; ++cc){
      __syncthreads();                         // prev chunk consumed (+A staged, 1st iter)
      // stage B chunk: Bc[code 0..63][k 0..127] from cbbf rows
#pragma unroll
      for (int j = 0; j < 4; ++j){
        int q = w*4 + j;                       // 0..15, 4 code-rows per instr
        int code = kt*64 + q*4 + quad;
        gl_lds16(cbbf + (size_t)code*512 + cc*128 + lc*8, &Bc[q*512 + lane*8]);
      }
      __syncthreads();                         // staged (barrier drains vmcnt)

      const int abase = lc*512 + cc*128 + quad*8;        // A[m=lc][k=quad*8+j]
      const int bbase = (w*16 + lc)*128 + quad*8;        // B[k=quad*8+j][n=lc]
#pragma unroll
      for (int ks = 0; ks < 4; ++ks){
        bf16x8 a_s = *(const bf16x8*)&As[abase + ks*32];
        bf16x8 a_t = *(const bf16x8*)&At[abase + ks*32];
        bf16x8 bb  = *(const bf16x8*)&Bc[bbase + ks*32];
        accS = __builtin_amdgcn_mfma_f32_16x16x32_bf16(a_s, bb, accS, 0, 0, 0);
        accT = __builtin_amdgcn_mfma_f32_16x16x32_bf16(a_t, bb, accT, 0, 0, 0);
      }
    }
    // ---- tile epilogue: logits l' = 2*x.c - |c|^2 ; online update ----
    float c2v = c2[kt*64 + w*16 + lc];
#pragma unroll
    for (int i = 0; i < 4; ++i){
      float sl = 2.0f*accS[i] - c2v;
      float tl = 2.0f*accT[i] - c2v;
      float nms = fmaxf(mS[i], sl);
      ZS[i] = ZS[i]*__expf(mS[i]-nms) + __expf(sl-nms);
      mS[i] = nms;
      float nmt = fmaxf(mT[i], tl);
      float e0 = __expf(mT[i]-nmt), e1 = __expf(tl-nmt);
      ZT[i] = ZT[i]*e0 + e1;
      AA[i] = AA[i]*e0 + e1*(tl - sl);
      mT[i] = nmt;
    }
    accS = (f32x4){0.f,0.f,0.f,0.f};
    accT = (f32x4){0.f,0.f,0.f,0.f};
  }

  // ---- merge 16 code-classes within each quad (exact softmax-state merge) ----
  for (int mm = 1; mm < 16; mm <<= 1){
#pragma unroll
    for (int i = 0; i < 4; ++i){
      float omS = __shfl_xor(mS[i], mm, 16);
      float oZS = __shfl_xor(ZS[i], mm, 16);
      float omT = __shfl_xor(mT[i], mm, 16);
      float oZT = __shfl_xor(ZT[i], mm, 16);
      float oA  = __shfl_xor(AA[i], mm, 16);
      float nms = fmaxf(mS[i], omS);
      ZS[i] = ZS[i]*__expf(mS[i]-nms) + oZS*__expf(omS-nms);
      mS[i] = nms;
      float nmt = fmaxf(mT[i], omT);
      float e0 = __expf(mT[i]-nmt), e1 = __expf(omT-nmt);
      ZT[i] = ZT[i]*e0 + oZT*e1;
      AA[i] = AA[i]*e0 + oA*e1;
      mT[i] = nmt;
    }
  }
  if (lc == 0){
#pragma unroll
    for (int i = 0; i < 4; ++i){
      int tok = quad*4 + i;
      wst[w][tok][0] = mS[i]; wst[w][tok][1] = ZS[i];
      wst[w][tok][2] = mT[i]; wst[w][tok][3] = ZT[i];
      wst[w][tok][4] = AA[i];
    }
  }
  __syncthreads();

  // ---- cross-wave merge + per-token KL / min-dist + block partials ----
  if (tid < 16){
    float m_s = wst[0][tid][0], z_s = wst[0][tid][1];
    float m_t = wst[0][tid][2], z_t = wst[0][tid][3], a = wst[0][tid][4];
#pragma unroll
    for (int ww = 1; ww < 4; ++ww){
      float omS = wst[ww][tid][0], oZS = wst[ww][tid][1];
      float omT = wst[ww][tid][2], oZT = wst[ww][tid][3], oA = wst[ww][tid][4];
      float nms = fmaxf(m_s, omS);
      z_s = z_s*__expf(m_s-nms) + oZS*__expf(omS-nms);
      m_s = nms;
      float nmt = fmaxf(m_t, omT);
      float e0 = __expf(m_t-nmt), e1 = __expf(omT-nmt);
      z_t = z_t*e0 + oZT*e1;
      a   = a*e0   + oA*e1;
      m_t = nmt;
    }
    // KL = A/Zt - (m_t + ln Zt) + (m_s + ln Zs); shifts cancel exactly
    float kl = a / z_t - (m_t + __logf(z_t)) + (m_s + __logf(z_s));
    int tokg = blk*16 + tid;
    int b = tokg / T_N, tt = tokg - b*T_N;
    int valid = lengths[b] / STRD; if (valid > T_N) valid = T_N;
    float maskf = (tt < valid) ? 1.f : 0.f;
    float sfp = kl * maskf;
    float cmp = x2s[tokg] - m_s;            // min ||x-c||^2 (all tokens, unmasked)
#pragma unroll
    for (int mm = 1; mm < 16; mm <<= 1){
      sfp += __shfl_xor(sfp, mm, 16);
      cmp += __shfl_xor(cmp, mm, 16);
    }
    if (tid == 0){ softP[blk] = sfp; commP[blk] = cmp; }
  }
}

// ============ finalize: deterministic double reduction ============
__global__ __launch_bounds__(256) void finalize_kernel(
    const float* __restrict__ featP, const float* __restrict__ tripP,
    const float* __restrict__ softP, const float* __restrict__ commP,
    const int* __restrict__ lengths, float* __restrict__ out)
{
  const int tid = threadIdx.x;
  double f = 0.0, tr = 0.0, sf = 0.0, cm = 0.0;
  for (int i = tid; i < 3000; i += 256){ f += (double)featP[i]; tr += (double)tripP[i]; }
  for (int i = tid; i < 750;  i += 256){ sf += (double)softP[i]; cm += (double)commP[i]; }
#pragma unroll
  for (int mm = 1; mm < 64; mm <<= 1){
    f  += __shfl_xor(f,  mm);
    tr += __shfl_xor(tr, mm);
    sf += __shfl_xor(sf, mm);
    cm += __shfl_xor(cm, mm);
  }
  __shared__ double red[4][4];
  const int w = tid >> 6, lane = tid & 63;
  if (lane == 0){ red[w][0]=f; red[w][1]=tr; red[w][2]=sf; red[w][3]=cm; }
  __syncthreads();
  if (tid == 0){
    double F=0,TR=0,SF=0,CM=0;
    for (int ww = 0; ww < 4; ++ww){ F+=red[ww][0]; TR+=red[ww][1]; SF+=red[ww][2]; CM+=red[ww][3]; }
    long msum = 0;
    for (int b = 0; b < 8; ++b){ int v = lengths[b] / STRD; if (v > T_N) v = T_N; msum += v; }
    double inv = 1.0 / (double)msum;
    double total = F*inv + TR*inv + SF*inv + 0.2 * CM / ((double)B_N * T_N * D_N);
    out[0] = (float)total;
  }
}

extern "C" void kernel_launch(void* const* d_in, const int* in_sizes, int n_in,
                              void* d_out, int out_size, void* d_ws, size_t ws_size,
                              hipStream_t stream)
{
  const float* s  = (const float*)d_in[0];
  const float* t  = (const float*)d_in[1];
  // d_in[2] = teacher_codes: unused by the reference computation
  const float* cb = (const float*)d_in[3];
  const int* lengths = (const int*)d_in[4];

  char* ws = (char*)d_ws;
  float* x2s   = (float*)(ws + X2S_OFF);
  float* c2    = (float*)(ws + C2_OFF);
  float* featP = (float*)(ws + FEATP_OFF);
  float* tripP = (float*)(ws + TRIPP_OFF);
  float* softP = (float*)(ws + SOFTP_OFF);
  float* commP = (float*)(ws + COMMP_OFF);
  u16* sbf  = (u16*)(ws + SBF_OFF);
  u16* tbf  = (u16*)(ws + TBF_OFF);
  u16* cbbf = (u16*)(ws + CBBF_OFF);

  prep_feat_kernel<<<3000, 256, 0, stream>>>(s, t, lengths, sbf, tbf, x2s, featP, tripP);
  prep_cb_kernel<<<1024, 256, 0, stream>>>(cb, cbbf, c2);
  main_kl_kernel<<<750, 256, 0, stream>>>(sbf, tbf, cbbf, c2, x2s, lengths, softP, commP);
  finalize_kernel<<<1, 256, 0, stream>>>(featP, tripP, softP, commP, lengths, (float*)d_out);
}

// Round 2
// 283.964 us; speedup vs baseline: 2.3200x; 2.3200x over previous
//
#include <hip/hip_runtime.h>

typedef unsigned short u16;
typedef unsigned int   u32;
typedef float  f32x4  __attribute__((ext_vector_type(4)));
typedef __bf16 bf16x8 __attribute__((ext_vector_type(8)));

#define B_N   8
#define T_N   1500
#define D_N   512
#define K_N   4096
#define NTOK  12000
#define STRD  320

// ---- workspace byte offsets (total ~28.9 MB) ----
#define X2S_OFF    0u                       // 12000 floats
#define C2_OFF     49152u                   // 4096 floats
#define FEATP_OFF  65536u                   // 3000 floats
#define TRIPP_OFF  81920u                   // 3000 floats
#define SOFTP_OFF  98304u                   // 750 floats
#define COMMP_OFF  106496u                  // 750 floats
#define SBF_OFF    131072u                  // 12000*512 u16 (bf16 student, tile-fragment order)
#define TBF_OFF    (131072u + 12288000u)    // 12000*512 u16 (bf16 teacher, tile-fragment order)
#define CBBF_OFF   (131072u + 24576000u)    // 4096*512 u16 (bf16 codebook, tile-fragment order)

// ---- tile-fragment global layouts (16B "chunks" of 8 bf16) ----
// sbf/tbf: chunk = blk*1024 + cc*256 + ks*64 + quad*16 + m
//   (token = blk*16+m, k-range = cc*128 + ks*32 + quad*8 .. +8)
// cbbf:    chunk = kt*4096 + cc*1024 + w*256 + ks*64 + quad*16 + lc
//   (code = kt*64 + w*16 + lc, same k mapping)
// => every ds_read_b128 and every global_load_lds is uniform_base + lane*16 (conflict-free)

__device__ __forceinline__ u16 f2bf(float x){
  u32 u = __float_as_uint(x);
  u32 r = (u + 0x7fffu + ((u >> 16) & 1u)) >> 16;   // round-nearest-even
  return (u16)r;
}

__device__ __forceinline__ void gl_lds16(const void* g, void* l){
  // async global->LDS, 16B/lane; LDS dest = wave-uniform base + lane*16
  __builtin_amdgcn_global_load_lds(
      (__attribute__((address_space(1))) void*)(g),
      (__attribute__((address_space(3))) void*)(l),
      16, 0, 0);
}

// ============ prep 1: per-token stats, bf16 casts (permuted), feature+triplet ============
__global__ __launch_bounds__(256) void prep_feat_kernel(
    const float* __restrict__ s, const float* __restrict__ t,
    const int* __restrict__ lengths,
    u16* __restrict__ sbf, u16* __restrict__ tbf,
    float* __restrict__ x2s,
    float* __restrict__ featP, float* __restrict__ tripP)
{
  const int tid = threadIdx.x;
  const int w = tid >> 6, lane = tid & 63;
  const int n = blockIdx.x * 4 + w;                 // one wave per token
  const int b = n / T_N, tt = n - b * T_N;
  const int nr = ((b + 7) & 7) * T_N + tt;          // roll(teacher, +1, axis=0)

  const float4* sp = (const float4*)(s + (size_t)n  * D_N);
  const float4* tp = (const float4*)(t + (size_t)n  * D_N);
  const float4* rp = (const float4*)(t + (size_t)nr * D_N);
  float4 s0 = sp[lane*2], s1 = sp[lane*2+1];
  float4 t0 = tp[lane*2], t1 = tp[lane*2+1];
  float4 r0 = rp[lane*2], r1 = rp[lane*2+1];

  float sv[8] = {s0.x,s0.y,s0.z,s0.w,s1.x,s1.y,s1.z,s1.w};
  float tv[8] = {t0.x,t0.y,t0.z,t0.w,t1.x,t1.y,t1.z,t1.w};
  float rv[8] = {r0.x,r0.y,r0.z,r0.w,r1.x,r1.y,r1.z,r1.w};

  float sd2 = 0.f, x2 = 0.f, nd2 = 0.f;
  u16 sb[8], tb[8];
#pragma unroll
  for (int i = 0; i < 8; ++i){
    float d = sv[i] - tv[i]; sd2 += d*d;
    x2 += sv[i]*sv[i];
    float e = sv[i] - rv[i]; nd2 += e*e;
    sb[i] = f2bf(sv[i]); tb[i] = f2bf(tv[i]);
  }
  uint4 spk, tpk;
  spk.x = (u32)sb[0] | ((u32)sb[1] << 16);
  spk.y = (u32)sb[2] | ((u32)sb[3] << 16);
  spk.z = (u32)sb[4] | ((u32)sb[5] << 16);
  spk.w = (u32)sb[6] | ((u32)sb[7] << 16);
  tpk.x = (u32)tb[0] | ((u32)tb[1] << 16);
  tpk.y = (u32)tb[2] | ((u32)tb[3] << 16);
  tpk.z = (u32)tb[4] | ((u32)tb[5] << 16);
  tpk.w = (u32)tb[6] | ((u32)tb[7] << 16);

  // permuted destination chunk: lane == k-chunk index (0..63)
  {
    const int cc = lane >> 4, ks = (lane >> 2) & 3, qd = lane & 3;
    const int blk = n >> 4, m = n & 15;
    const size_t dchunk = (size_t)blk*1024 + cc*256 + ks*64 + qd*16 + m;
    ((uint4*)sbf)[dchunk] = spk;
    ((uint4*)tbf)[dchunk] = tpk;
  }

#pragma unroll
  for (int mm = 1; mm < 64; mm <<= 1){
    sd2 += __shfl_xor(sd2, mm);
    x2  += __shfl_xor(x2,  mm);
    nd2 += __shfl_xor(nd2, mm);
  }

  __shared__ float af[4], atr[4];
  if (lane == 0){
    x2s[n] = x2;
    int valid = lengths[b] / STRD; if (valid > T_N) valid = T_N;
    float mf = (tt < valid) ? 1.f : 0.f;
    af[w]  = mf * sd2 * (1.f/512.f);
    atr[w] = mf * fmaxf(sqrtf(sd2) - sqrtf(nd2) + 0.2f, 0.f);
  }
  __syncthreads();
  if (tid == 0){
    featP[blockIdx.x] = af[0]+af[1]+af[2]+af[3];
    tripP[blockIdx.x] = atr[0]+atr[1]+atr[2]+atr[3];
  }
}

// ============ prep 2: codebook norms + bf16 cast (permuted) ============
__global__ __launch_bounds__(256) void prep_cb_kernel(
    const float* __restrict__ cb, u16* __restrict__ cbbf, float* __restrict__ c2)
{
  const int tid = threadIdx.x;
  const int w = tid >> 6, lane = tid & 63;
  const int k = blockIdx.x * 4 + w;                 // one wave per code

  const float4* cp = (const float4*)(cb + (size_t)k * D_N);
  float4 c0 = cp[lane*2], c1 = cp[lane*2+1];
  float cv[8] = {c0.x,c0.y,c0.z,c0.w,c1.x,c1.y,c1.z,c1.w};

  float s2 = 0.f;
  u16 cbv[8];
#pragma unroll
  for (int i = 0; i < 8; ++i){ s2 += cv[i]*cv[i]; cbv[i] = f2bf(cv[i]); }
  uint4 pk;
  pk.x = (u32)cbv[0] | ((u32)cbv[1] << 16);
  pk.y = (u32)cbv[2] | ((u32)cbv[3] << 16);
  pk.z = (u32)cbv[4] | ((u32)cbv[5] << 16);
  pk.w = (u32)cbv[6] | ((u32)cbv[7] << 16);

  {
    const int cc = lane >> 4, ks = (lane >> 2) & 3, qd = lane & 3;
    const int kt = k >> 6, wb = (k >> 4) & 3, lcb = k & 15;
    const size_t dchunk = (size_t)kt*4096 + cc*1024 + wb*256 + ks*64 + qd*16 + lcb;
    ((uint4*)cbbf)[dchunk] = pk;
  }

#pragma unroll
  for (int mm = 1; mm < 64; mm <<= 1) s2 += __shfl_xor(s2, mm);
  if (lane == 0) c2[k] = s2;
}

// ============ main: fused dual-GEMM + online-softmax KL + min-dist ============
__global__ __launch_bounds__(256, 3) void main_kl_kernel(
    const u16* __restrict__ sbf, const u16* __restrict__ tbf,
    const u16* __restrict__ cbbf, const float* __restrict__ c2,
    const float* __restrict__ x2s, const int* __restrict__ lengths,
    float* __restrict__ softP, float* __restrict__ commP)
{
  __shared__ u16 As[16*512];      // 16 KB (tile-fragment order)
  __shared__ u16 At[16*512];      // 16 KB
  __shared__ u16 Bc[64*128];      // 16 KB
  __shared__ float wst[4][16][5]; // cross-wave merge buffer

  const int tid  = threadIdx.x;
  const int w    = tid >> 6, lane = tid & 63;
  const int quad = lane >> 4, lc = lane & 15;
  const int blk  = blockIdx.x;
  const int lane8 = lane * 8;

  // ---- stage A (once): contiguous copy, global order == LDS fragment order ----
  {
    const u16* sg = sbf + (size_t)blk * 16 * 512;
    const u16* tg = tbf + (size_t)blk * 16 * 512;
#pragma unroll
    for (int j = 0; j < 4; ++j){
      int off = (w*4 + j)*512 + lane8;   // 1KB chunks, lane*16B inside
      gl_lds16(sg + off, &As[off]);
      gl_lds16(tg + off, &At[off]);
    }
  }

  // per-lane online-softmax partial state: tokens quad*4+i, codes == (w, lc)
  float mS[4], ZS[4], mT[4], ZT[4], AA[4];
#pragma unroll
  for (int i = 0; i < 4; ++i){ mS[i] = -1e30f; mT[i] = -1e30f; ZS[i]=0.f; ZT[i]=0.f; AA[i]=0.f; }

  f32x4 accS = {0.f,0.f,0.f,0.f}, accT = {0.f,0.f,0.f,0.f};

  for (int kt = 0; kt < 64; ++kt){
    for (int cc = 0; cc < 4; ++cc){
      __syncthreads();                         // prev chunk consumed (+A staged, 1st iter)
      // stage B chunk (kt, cc): contiguous 16KB copy in fragment order
      {
        const u16* bg = cbbf + (size_t)(kt*4 + cc) * 8192;
#pragma unroll
        for (int j = 0; j < 4; ++j){
          int off = (w*4 + j)*512 + lane8;
          gl_lds16(bg + off, &Bc[off]);
        }
      }
      __syncthreads();                         // staged (barrier drains vmcnt)

#pragma unroll
      for (int ks = 0; ks < 4; ++ks){
        bf16x8 a_s = *(const bf16x8*)&As[cc*2048 + ks*512 + lane8];
        bf16x8 a_t = *(const bf16x8*)&At[cc*2048 + ks*512 + lane8];
        bf16x8 bb  = *(const bf16x8*)&Bc[w*2048  + ks*512 + lane8];
        accS = __builtin_amdgcn_mfma_f32_16x16x32_bf16(a_s, bb, accS, 0, 0, 0);
        accT = __builtin_amdgcn_mfma_f32_16x16x32_bf16(a_t, bb, accT, 0, 0, 0);
      }
    }
    // ---- tile epilogue: logits l' = 2*x.c - |c|^2 ; online update ----
    float c2v = c2[kt*64 + w*16 + lc];
#pragma unroll
    for (int i = 0; i < 4; ++i){
      float sl = 2.0f*accS[i] - c2v;
      float tl = 2.0f*accT[i] - c2v;
      float nms = fmaxf(mS[i], sl);
      ZS[i] = ZS[i]*__expf(mS[i]-nms) + __expf(sl-nms);
      mS[i] = nms;
      float nmt = fmaxf(mT[i], tl);
      float e0 = __expf(mT[i]-nmt), e1 = __expf(tl-nmt);
      ZT[i] = ZT[i]*e0 + e1;
      AA[i] = AA[i]*e0 + e1*(tl - sl);
      mT[i] = nmt;
    }
    accS = (f32x4){0.f,0.f,0.f,0.f};
    accT = (f32x4){0.f,0.f,0.f,0.f};
  }

  // ---- merge 16 code-classes within each quad (exact softmax-state merge) ----
  for (int mm = 1; mm < 16; mm <<= 1){
#pragma unroll
    for (int i = 0; i < 4; ++i){
      float omS = __shfl_xor(mS[i], mm, 16);
      float oZS = __shfl_xor(ZS[i], mm, 16);
      float omT = __shfl_xor(mT[i], mm, 16);
      float oZT = __shfl_xor(ZT[i], mm, 16);
      float oA  = __shfl_xor(AA[i], mm, 16);
      float nms = fmaxf(mS[i], omS);
      ZS[i] = ZS[i]*__expf(mS[i]-nms) + oZS*__expf(omS-nms);
      mS[i] = nms;
      float nmt = fmaxf(mT[i], omT);
      float e0 = __expf(mT[i]-nmt), e1 = __expf(omT-nmt);
      ZT[i] = ZT[i]*e0 + oZT*e1;
      AA[i] = AA[i]*e0 + oA*e1;
      mT[i] = nmt;
    }
  }
  if (lc == 0){
#pragma unroll
    for (int i = 0; i < 4; ++i){
      int tok = quad*4 + i;
      wst[w][tok][0] = mS[i]; wst[w][tok][1] = ZS[i];
      wst[w][tok][2] = mT[i]; wst[w][tok][3] = ZT[i];
      wst[w][tok][4] = AA[i];
    }
  }
  __syncthreads();

  // ---- cross-wave merge + per-token KL / min-dist + block partials ----
  if (tid < 16){
    float m_s = wst[0][tid][0], z_s = wst[0][tid][1];
    float m_t = wst[0][tid][2], z_t = wst[0][tid][3], a = wst[0][tid][4];
#pragma unroll
    for (int ww = 1; ww < 4; ++ww){
      float omS = wst[ww][tid][0], oZS = wst[ww][tid][1];
      float omT = wst[ww][tid][2], oZT = wst[ww][tid][3], oA = wst[ww][tid][4];
      float nms = fmaxf(m_s, omS);
      z_s = z_s*__expf(m_s-nms) + oZS*__expf(omS-nms);
      m_s = nms;
      float nmt = fmaxf(m_t, omT);
      float e0 = __expf(m_t-nmt), e1 = __expf(omT-nmt);
      z_t = z_t*e0 + oZT*e1;
      a   = a*e0   + oA*e1;
      m_t = nmt;
    }
    // KL = A/Zt - (m_t + ln Zt) + (m_s + ln Zs); shifts cancel exactly
    float kl = a / z_t - (m_t + __logf(z_t)) + (m_s + __logf(z_s));
    int tokg = blk*16 + tid;
    int b = tokg / T_N, tt = tokg - b*T_N;
    int valid = lengths[b] / STRD; if (valid > T_N) valid = T_N;
    float maskf = (tt < valid) ? 1.f : 0.f;
    float sfp = kl * maskf;
    float cmp = x2s[tokg] - m_s;            // min ||x-c||^2 (all tokens, unmasked)
#pragma unroll
    for (int mm = 1; mm < 16; mm <<= 1){
      sfp += __shfl_xor(sfp, mm, 16);
      cmp += __shfl_xor(cmp, mm, 16);
    }
    if (tid == 0){ softP[blk] = sfp; commP[blk] = cmp; }
  }
}

// ============ finalize: deterministic double reduction ============
__global__ __launch_bounds__(256) void finalize_kernel(
    const float* __restrict__ featP, const float* __restrict__ tripP,
    const float* __restrict__ softP, const float* __restrict__ commP,
    const int* __restrict__ lengths, float* __restrict__ out)
{
  const int tid = threadIdx.x;
  double f = 0.0, tr = 0.0, sf = 0.0, cm = 0.0;
  for (int i = tid; i < 3000; i += 256){ f += (double)featP[i]; tr += (double)tripP[i]; }
  for (int i = tid; i < 750;  i += 256){ sf += (double)softP[i]; cm += (double)commP[i]; }
#pragma unroll
  for (int mm = 1; mm < 64; mm <<= 1){
    f  += __shfl_xor(f,  mm);
    tr += __shfl_xor(tr, mm);
    sf += __shfl_xor(sf, mm);
    cm += __shfl_xor(cm, mm);
  }
  __shared__ double red[4][4];
  const int w = tid >> 6, lane = tid & 63;
  if (lane == 0){ red[w][0]=f; red[w][1]=tr; red[w][2]=sf; red[w][3]=cm; }
  __syncthreads();
  if (tid == 0){
    double F=0,TR=0,SF=0,CM=0;
    for (int ww = 0; ww < 4; ++ww){ F+=red[ww][0]; TR+=red[ww][1]; SF+=red[ww][2]; CM+=red[ww][3]; }
    long msum = 0;
    for (int b = 0; b < 8; ++b){ int v = lengths[b] / STRD; if (v > T_N) v = T_N; msum += v; }
    double inv = 1.0 / (double)msum;
    double total = F*inv + TR*inv + SF*inv + 0.2 * CM / ((double)B_N * T_N * D_N);
    out[0] = (float)total;
  }
}

extern "C" void kernel_launch(void* const* d_in, const int* in_sizes, int n_in,
                              void* d_out, int out_size, void* d_ws, size_t ws_size,
                              hipStream_t stream)
{
  const float* s  = (const float*)d_in[0];
  const float* t  = (const float*)d_in[1];
  // d_in[2] = teacher_codes: unused by the reference computation
  const float* cb = (const float*)d_in[3];
  const int* lengths = (const int*)d_in[4];

  char* ws = (char*)d_ws;
  float* x2s   = (float*)(ws + X2S_OFF);
  float* c2    = (float*)(ws + C2_OFF);
  float* featP = (float*)(ws + FEATP_OFF);
  float* tripP = (float*)(ws + TRIPP_OFF);
  float* softP = (float*)(ws + SOFTP_OFF);
  float* commP = (float*)(ws + COMMP_OFF);
  u16* sbf  = (u16*)(ws + SBF_OFF);
  u16* tbf  = (u16*)(ws + TBF_OFF);
  u16* cbbf = (u16*)(ws + CBBF_OFF);

  prep_feat_kernel<<<3000, 256, 0, stream>>>(s, t, lengths, sbf, tbf, x2s, featP, tripP);
  prep_cb_kernel<<<1024, 256, 0, stream>>>(cb, cbbf, c2);
  main_kl_kernel<<<750, 256, 0, stream>>>(sbf, tbf, cbbf, c2, x2s, lengths, softP, commP);
  finalize_kernel<<<1, 256, 0, stream>>>(featP, tripP, softP, commP, lengths, (float*)d_out);
}